// Round 11
// baseline (346.989 us; speedup 1.0000x reference)
//
#include <hip/hip_runtime.h>

// ROI max-pooling, TF-style integer binning (matches the JAX reference).
// Round 11: EXACT XCD pinning via HW_REG_XCC_ID (hwreg 20, verified on
// MI355X) + persistent grid + per-image atomic work queues in d_ws.
// 2048 blocks x 256 thr (8/CU, all resident). Block's waves serve the image
// owned by their XCD pair (img = xcc>>1); steal passes guarantee
// completeness even if the XCC read misbehaves. Work item = (roi, row-bin)
// strip (R7's amortized 7-col-accumulator inner loop, wstep-specialized).
// Counters zeroed per launch via hipMemsetAsync (graph-capture legal).
// Nontemporal stores for the output.

#define OUT_H 7
#define OUT_W 7
#define NBIN (OUT_H * OUT_W)   // 49
#define NB 4
#define NR 64
#define NH 56
#define NW 56
#define NC 256
#define C4 (NC / 4)            // 64 float4 groups per pixel

#define NSTRIPS (NR * OUT_H)   // 448 work items per image: (r, oi)

typedef float v4f __attribute__((ext_vector_type(4)));

__device__ __forceinline__ v4f vmax4(v4f a, v4f b) {
    v4f r;
    r.x = fmaxf(a.x, b.x);
    r.y = fmaxf(a.y, b.y);
    r.z = fmaxf(a.z, b.z);
    r.w = fmaxf(a.w, b.w);
    return r;
}

// Pool rows [rlo, rhi) over all 7 column bins (R7's proven inner loop).
// WS > 0: compile-time wstep. WS == 0: generic/degenerate fallback.
template <int WS>
__device__ __forceinline__ void pool_rows(
    const v4f* __restrict__ base, int rlo, int rhi,
    int w0, int w1, int wstep_rt, v4f* acc)
{
    const int ws = (WS > 0) ? WS : wstep_rt;
    for (int h = rlo; h < rhi; ++h) {
        const v4f* rowp = base + (size_t)(h * NW) * C4;
#pragma unroll
        for (int j = 0; j < OUT_W - 1; ++j) {
            const int wb = w0 + j * ws;
            if (WS > 0) {
#pragma unroll
                for (int k = 0; k < WS; ++k)
                    acc[j] = vmax4(acc[j], rowp[(size_t)(wb + k) * C4]);
            } else {
                for (int w = wb; w < wb + ws; ++w)
                    acc[j] = vmax4(acc[j], rowp[(size_t)w * C4]);
            }
        }
        for (int w = w0 + 6 * ws; w < w1; ++w)
            acc[6] = vmax4(acc[6], rowp[(size_t)w * C4]);
    }
}

__device__ __forceinline__ void process_strip(
    const float* __restrict__ fmap, const float* __restrict__ rois,
    float* __restrict__ out, int b, int it, int lane)
{
    const int r  = it / OUT_H;
    const int oi = it - r * OUT_H;   // row bin

    const float* roi = rois + (size_t)(b * NR + r) * 4;
    const float r0 = roi[0], r1 = roi[1], r2 = roi[2], r3 = roi[3];
    const int h0 = (int)((float)NH * r0);
    const int w0 = (int)((float)NW * r1);
    const int h1 = (int)((float)NH * r2);
    const int w1 = (int)((float)NW * r3);

    const int hstep = (int)((float)(h1 - h0) / (float)OUT_H);
    const int wstep = (int)((float)(w1 - w0) / (float)OUT_W);

    int rlo, rhi;
    if (hstep >= 1) {
        rlo = h0 + oi * hstep;
        rhi = (oi < OUT_H - 1) ? (rlo + hstep) : h1;
    } else {
        rlo = (oi == OUT_H - 1) ? h0 : 0;
        rhi = (oi == OUT_H - 1) ? h1 : 0;
    }

    const v4f* base =
        (const v4f*)(fmap + (size_t)b * NH * NW * NC) + lane;

    const v4f ninf = (v4f){-INFINITY, -INFINITY, -INFINITY, -INFINITY};
    v4f acc[OUT_W];
#pragma unroll
    for (int j = 0; j < OUT_W; ++j) acc[j] = ninf;

    switch (wstep) {
        case 2: pool_rows<2>(base, rlo, rhi, w0, w1, wstep, acc); break;
        case 3: pool_rows<3>(base, rlo, rhi, w0, w1, wstep, acc); break;
        case 4: pool_rows<4>(base, rlo, rhi, w0, w1, wstep, acc); break;
        default: pool_rows<0>(base, rlo, rhi, w0, w1, wstep, acc); break;
    }

    const size_t obase = ((size_t)((b * NR + r) * NBIN + oi * OUT_W)) * NC;
#pragma unroll
    for (int j = 0; j < OUT_W; ++j) {
        v4f* o = (v4f*)(out + obase + (size_t)j * NC);
        __builtin_nontemporal_store(acc[j], o + lane);
    }
}

__global__ __launch_bounds__(256, 8) void roi_pool_kernel(
    const float* __restrict__ fmap,   // [B,H,W,C]
    const float* __restrict__ rois,   // [B,R,4]
    float* __restrict__ out,          // [B,R,7,7,C]
    int* __restrict__ q)              // [4] per-image work counters (zeroed)
{
    const int lane = threadIdx.x & 63;

    // Hardware XCD id (0..7): hwreg id 20 = HW_REG_XCC_ID (gfx940+/gfx950).
    unsigned xcc;
    asm volatile("s_getreg_b32 %0, hwreg(20, 0, 32)" : "=s"(xcc));
    const int img0 = (int)((xcc >> 1) & 3);   // image owned by this XCD pair

    // Own image first; then steal passes (correctness-safe if xcc is junk).
    for (int p = 0; p < NB; ++p) {
        const int b = (img0 + p) & 3;
        while (true) {
            // cheap pre-check: skip the RMW when the queue is drained
            if (*(volatile int*)&q[b] >= NSTRIPS) break;
            int it = 0;
            if (lane == 0) it = atomicAdd(&q[b], 1);
            it = __shfl(it, 0);
            if (it >= NSTRIPS) break;
            process_strip(fmap, rois, out, b, it, lane);
        }
    }
}

extern "C" void kernel_launch(void* const* d_in, const int* in_sizes, int n_in,
                              void* d_out, int out_size, void* d_ws, size_t ws_size,
                              hipStream_t stream) {
    const float* fmap = (const float*)d_in[0];
    const float* rois = (const float*)d_in[1];
    float* out = (float*)d_out;
    int* q = (int*)d_ws;

    // zero the 4 work-queue counters (graph-capture-legal async memset)
    hipMemsetAsync(q, 0, 4 * sizeof(int), stream);

    roi_pool_kernel<<<2048, 256, 0, stream>>>(fmap, rois, out, q);
}

// Round 12
// 43.060 us; speedup vs baseline: 8.0583x; 8.0583x over previous
//
#include <hip/hip_runtime.h>

// ROI max-pooling, TF-style integer binning (matches the JAX reference).
// Round 12: EXACT XCD pinning with minimal overhead. Each block reads its
// hardware XCD id (HW_REG_XCC_ID, hwreg 20 — HW-verified on MI355X) and takes
// ONE atomicAdd on its per-XCD counter (2048 atomics total, 8 lines — no
// polling, no stealing; R11's storm came from per-wave grabs + volatile
// spins). XCD x serves image x>>1. rank < 224 -> block processes strip
// (roi, row-bin) = ((x&1)*224 + rank); 7 col-bins split over 4 waves
// (waves 0..3 -> col-bins {0,4},{1,5},{2,6},{3}). Inner loop = R5's compact
// 2x2/4-acc window. Surplus ranks (>=224) exit. Coverage requires >=224 of
// the nominal 256 blocks per XCD; a violation fails validation loudly.
// Nontemporal output stores kept.

#define OUT_H 7
#define OUT_W 7
#define NBIN (OUT_H * OUT_W)   // 49
#define NB 4
#define NR 64
#define NH 56
#define NW 56
#define NC 256
#define C4 (NC / 4)            // 64 float4 groups per pixel

#define RANKS_PER_XCD 224
#define NBLOCKS 2048           // 8 blocks/CU, fully resident

typedef float v4f __attribute__((ext_vector_type(4)));

__device__ __forceinline__ v4f vmax4(v4f a, v4f b) {
    v4f r;
    r.x = fmaxf(a.x, b.x);
    r.y = fmaxf(a.y, b.y);
    r.z = fmaxf(a.z, b.z);
    r.w = fmaxf(a.w, b.w);
    return r;
}

// R5's compact window loop: 2 rows x 2 cols unrolled, 4 independent accs.
__device__ __forceinline__ v4f pool_window(
    const v4f* __restrict__ base, int rlo, int rhi, int clo, int chi)
{
    const v4f ninf = (v4f){-INFINITY, -INFINITY, -INFINITY, -INFINITY};
    v4f acc0 = ninf, acc1 = ninf, acc2 = ninf, acc3 = ninf;

    int h = rlo;
    for (; h + 1 < rhi; h += 2) {
        const v4f* r0p = base + (size_t)(h * NW) * C4;
        const v4f* r1p = r0p + (size_t)NW * C4;
        int w = clo;
        for (; w + 1 < chi; w += 2) {
            acc0 = vmax4(acc0, r0p[(size_t)w * C4]);
            acc1 = vmax4(acc1, r0p[(size_t)(w + 1) * C4]);
            acc2 = vmax4(acc2, r1p[(size_t)w * C4]);
            acc3 = vmax4(acc3, r1p[(size_t)(w + 1) * C4]);
        }
        if (w < chi) {
            acc0 = vmax4(acc0, r0p[(size_t)w * C4]);
            acc2 = vmax4(acc2, r1p[(size_t)w * C4]);
        }
    }
    if (h < rhi) {
        const v4f* r0p = base + (size_t)(h * NW) * C4;
        int w = clo;
        for (; w + 1 < chi; w += 2) {
            acc0 = vmax4(acc0, r0p[(size_t)w * C4]);
            acc1 = vmax4(acc1, r0p[(size_t)(w + 1) * C4]);
        }
        if (w < chi) acc0 = vmax4(acc0, r0p[(size_t)w * C4]);
    }
    return vmax4(vmax4(acc0, acc1), vmax4(acc2, acc3));
}

__global__ __launch_bounds__(256, 8) void roi_pool_kernel(
    const float* __restrict__ fmap,   // [B,H,W,C]
    const float* __restrict__ rois,   // [B,R,4]
    float* __restrict__ out,          // [B,R,7,7,C]
    int* __restrict__ cnt8)           // [8] per-XCD block counters (zeroed)
{
    __shared__ int s_rank;

    // Hardware XCD id (0..7): hwreg id 20 = HW_REG_XCC_ID (gfx940+/gfx950).
    unsigned xcc;
    asm volatile("s_getreg_b32 %0, hwreg(20, 0, 32)" : "=s"(xcc));
    const int x = (int)(xcc & 7u);

    if (threadIdx.x == 0) s_rank = atomicAdd(&cnt8[x], 1);
    __syncthreads();
    const int rank = s_rank;
    if (rank >= RANKS_PER_XCD) return;   // surplus block: no work

    const int b     = x >> 1;                          // image owned by pair
    const int strip = (x & 1) * RANKS_PER_XCD + rank;  // [0,448)
    const int r     = strip / OUT_H;                   // roi
    const int oi    = strip - r * OUT_H;               // row bin

    const int wid  = threadIdx.x >> 6;   // wave -> col-bins {wid, wid+4}
    const int lane = threadIdx.x & 63;   // float4 channel group

    const float* roi = rois + (size_t)(b * NR + r) * 4;
    const float r0 = roi[0], r1 = roi[1], r2 = roi[2], r3 = roi[3];
    const int h0 = (int)((float)NH * r0);
    const int w0 = (int)((float)NW * r1);
    const int h1 = (int)((float)NH * r2);
    const int w1 = (int)((float)NW * r3);

    const int hstep = (int)((float)(h1 - h0) / (float)OUT_H);
    const int wstep = (int)((float)(w1 - w0) / (float)OUT_W);

    int rlo, rhi;
    if (hstep >= 1) {
        rlo = h0 + oi * hstep;
        rhi = (oi < OUT_H - 1) ? (rlo + hstep) : h1;
    } else {
        rlo = (oi == OUT_H - 1) ? h0 : 0;
        rhi = (oi == OUT_H - 1) ? h1 : 0;
    }

    const v4f* base =
        (const v4f*)(fmap + (size_t)b * NH * NW * NC) + lane;
    const size_t obase0 = ((size_t)((b * NR + r) * NBIN + oi * OUT_W)) * NC;

#pragma unroll
    for (int t = 0; t < 2; ++t) {
        const int oj = wid + t * 4;
        if (oj >= OUT_W) break;          // wave 3 has only one col-bin

        int clo, chi;
        if (wstep >= 1) {
            clo = w0 + oj * wstep;
            chi = (oj < OUT_W - 1) ? (clo + wstep) : w1;
        } else {
            clo = (oj == OUT_W - 1) ? w0 : 0;
            chi = (oj == OUT_W - 1) ? w1 : 0;
        }

        const v4f m = pool_window(base, rlo, rhi, clo, chi);

        v4f* o = (v4f*)(out + obase0 + (size_t)oj * NC);
        __builtin_nontemporal_store(m, o + lane);
    }
}

extern "C" void kernel_launch(void* const* d_in, const int* in_sizes, int n_in,
                              void* d_out, int out_size, void* d_ws, size_t ws_size,
                              hipStream_t stream) {
    const float* fmap = (const float*)d_in[0];
    const float* rois = (const float*)d_in[1];
    float* out = (float*)d_out;
    int* cnt8 = (int*)d_ws;

    // zero the 8 per-XCD counters (graph-capture-legal async memset)
    hipMemsetAsync(cnt8, 0, 8 * sizeof(int), stream);

    roi_pool_kernel<<<NBLOCKS, 256, 0, stream>>>(fmap, rois, out, cnt8);
}

// Round 13
// 17.669 us; speedup vs baseline: 19.6380x; 2.4370x over previous
//
#include <hip/hip_runtime.h>

// ROI max-pooling, TF-style integer binning (matches the JAX reference).
// Round 13: R10 base (1568 blocks x 256 thr, fully resident; permuted
// 2 bins/wave for balance; %8 image pinning; NT stores) with the window
// loop replaced by a software-pipelined batch loop:
//  - window padded up to even dims by CLAMPING row/col indices (max is
//    idempotent, duplicate loads hit the same line) -> uniform row-pair x
//    col-pair batch grid, no tail code;
//  - batch i+1's 4 loads are issued before batch i's maxes consume them
//    -> 8 loads in flight steady-state (vs 4 in R5/R10), at ~60 VGPR so
//    occupancy stays 8 waves/SIMD.
// Tests whether the 15.7-16.3 us plateau is per-wave-concurrency-bound.

#define OUT_H 7
#define OUT_W 7
#define NBIN (OUT_H * OUT_W)   // 49
#define NB 4
#define NR 64
#define NH 56
#define NW 56
#define NC 256
#define C4 (NC / 4)            // 64 float4 groups per pixel

#define NBLOCKS 1568           // fully resident; 196 per XCD
#define BLKS_PER_XCD_SLOT 196
#define BINS_PER_IMG (NR * NBIN)   // 3136
#define PERM_MUL 597           // coprime to 3136

typedef float v4f __attribute__((ext_vector_type(4)));

__device__ __forceinline__ v4f vmax4(v4f a, v4f b) {
    v4f r;
    r.x = fmaxf(a.x, b.x);
    r.y = fmaxf(a.y, b.y);
    r.z = fmaxf(a.z, b.z);
    r.w = fmaxf(a.w, b.w);
    return r;
}

// Software-pipelined window max: clamp-padded 2x2 batches, double-buffered.
__device__ __forceinline__ v4f pool_window_db(
    const v4f* __restrict__ base, int rlo, int rhi, int clo, int chi)
{
    const v4f ninf = (v4f){-INFINITY, -INFINITY, -INFINITY, -INFINITY};
    const int nh = rhi - rlo, nw = chi - clo;
    if (nh <= 0 || nw <= 0) return ninf;   // degenerate bin -> -inf

    const int nbw = (nw + 1) >> 1;         // col-pair batches
    const int nbh = (nh + 1) >> 1;         // row-pair batches
    const int nbatch = nbh * nbw;
    const int hlast = rhi - 1, wlast = chi - 1;

    v4f acc0 = ninf, acc1 = ninf, acc2 = ninf, acc3 = ninf;

    // load batch (BH,BW) with clamped second row/col (idempotent for max)
#define LOAD_BATCH(BH, BW, x0, x1, x2, x3)                                  \
    {                                                                       \
        const int ha = rlo + 2 * (BH);                                      \
        const int hb = (ha + 1 <= hlast) ? ha + 1 : hlast;                  \
        const int wa = clo + 2 * (BW);                                      \
        const int wb = (wa + 1 <= wlast) ? wa + 1 : wlast;                  \
        const v4f* ra = base + (size_t)(ha * NW) * C4;                      \
        const v4f* rb = base + (size_t)(hb * NW) * C4;                      \
        x0 = ra[(size_t)wa * C4];                                           \
        x1 = ra[(size_t)wb * C4];                                           \
        x2 = rb[(size_t)wa * C4];                                           \
        x3 = rb[(size_t)wb * C4];                                           \
    }

    v4f a0, a1, a2, a3;
    LOAD_BATCH(0, 0, a0, a1, a2, a3);
    int bh = 0, bw = 0;
    for (int i = 1; i < nbatch; ++i) {
        ++bw;
        if (bw == nbw) { bw = 0; ++bh; }
        v4f b0, b1, b2, b3;
        LOAD_BATCH(bh, bw, b0, b1, b2, b3);   // issue before consuming a*
        acc0 = vmax4(acc0, a0);
        acc1 = vmax4(acc1, a1);
        acc2 = vmax4(acc2, a2);
        acc3 = vmax4(acc3, a3);
        a0 = b0; a1 = b1; a2 = b2; a3 = b3;
    }
    acc0 = vmax4(acc0, a0);
    acc1 = vmax4(acc1, a1);
    acc2 = vmax4(acc2, a2);
    acc3 = vmax4(acc3, a3);
#undef LOAD_BATCH
    return vmax4(vmax4(acc0, acc1), vmax4(acc2, acc3));
}

__global__ __launch_bounds__(256, 8) void roi_pool_kernel(
    const float* __restrict__ fmap,   // [B,H,W,C]
    const float* __restrict__ rois,   // [B,R,4]
    float* __restrict__ out)          // [B,R,7,7,C]
{
    const int blk  = blockIdx.x;
    const int xcd  = blk & 7;          // image b -> XCD pair {2b, 2b+1}
    const int b    = xcd >> 1;
    const int wid  = threadIdx.x >> 6; // wave id 0..3
    const int lane = threadIdx.x & 63; // float4 channel group

    // image-local wave id in [0, 1568): handles bins perm(2*iw), perm(2*iw+1)
    const int ibl = ((xcd & 1) * BLKS_PER_XCD_SLOT) + (blk >> 3); // [0,392)
    const int iw  = ibl * 4 + wid;                               // [0,1568)

    const v4f* base =
        (const v4f*)(fmap + (size_t)b * NH * NW * NC) + lane;
    const float* roib = rois + (size_t)b * NR * 4;

#pragma unroll
    for (int t = 0; t < 2; ++t) {
        const int j    = 2 * iw + t;                       // [0, 3136)
        const int gbin = (j * PERM_MUL) % BINS_PER_IMG;    // permuted bin id
        const int r    = gbin / NBIN;
        const int bin  = gbin - r * NBIN;
        const int oi   = bin / OUT_W;
        const int oj   = bin - oi * OUT_W;

        const float* roi = roib + (size_t)r * 4;
        const float r0 = roi[0], r1 = roi[1], r2 = roi[2], r3 = roi[3];
        const int h0 = (int)((float)NH * r0);
        const int w0 = (int)((float)NW * r1);
        const int h1 = (int)((float)NH * r2);
        const int w1 = (int)((float)NW * r3);

        const int hstep = (int)((float)(h1 - h0) / (float)OUT_H);
        const int wstep = (int)((float)(w1 - w0) / (float)OUT_W);

        int rlo, rhi, clo, chi;
        if (hstep >= 1) {
            rlo = h0 + oi * hstep;
            rhi = (oi < OUT_H - 1) ? (rlo + hstep) : h1;
        } else {
            rlo = (oi == OUT_H - 1) ? h0 : 0;
            rhi = (oi == OUT_H - 1) ? h1 : 0;
        }
        if (wstep >= 1) {
            clo = w0 + oj * wstep;
            chi = (oj < OUT_W - 1) ? (clo + wstep) : w1;
        } else {
            clo = (oj == OUT_W - 1) ? w0 : 0;
            chi = (oj == OUT_W - 1) ? w1 : 0;
        }

        const v4f m = pool_window_db(base, rlo, rhi, clo, chi);

        // output index uses LOGICAL ids (b, r, bin)
        const size_t obase = ((size_t)((b * NR + r) * NBIN + bin)) * NC;
        v4f* o = (v4f*)(out + obase);
        __builtin_nontemporal_store(m, o + lane);
    }
}

extern "C" void kernel_launch(void* const* d_in, const int* in_sizes, int n_in,
                              void* d_out, int out_size, void* d_ws, size_t ws_size,
                              hipStream_t stream) {
    const float* fmap = (const float*)d_in[0];
    const float* rois = (const float*)d_in[1];
    float* out = (float*)d_out;

    roi_pool_kernel<<<NBLOCKS, 256, 0, stream>>>(fmap, rois, out);
}